// Round 6
// baseline (505.783 us; speedup 1.0000x reference)
//
#include <hip/hip_runtime.h>
#include <hip/hip_bf16.h>

typedef unsigned int  uint32;
typedef unsigned short ushort16;
typedef __bf16 bfx8 __attribute__((ext_vector_type(8)));
typedef float  f32x4 __attribute__((ext_vector_type(4)));

#define B_   32
#define NQ_  300
#define D_   256
#define H_   8
#define HD_  32
#define L_   3
#define P_   4
#define S_   8400
#define FFN_ 1024
#define M1   (B_*NQ_)    // 9600
#define MV   (B_*S_)     // 268800
#define NQP  320
#define NQT  19

// ---------- helpers ----------
__device__ inline ushort16 f2bf(float x) {
  uint32 u = __float_as_uint(x);
  uint32 r = u + 0x7fffu + ((u >> 16) & 1u);
  return (ushort16)(r >> 16);
}
__device__ inline float bf2f(ushort16 v) {
  return __uint_as_float(((uint32)v) << 16);
}
__device__ inline uint32 cvtpk(float lo, float hi) {
  uint32 r; asm("v_cvt_pk_bf16_f32 %0, %1, %2" : "=v"(r) : "v"(lo), "v"(hi)); return r;
}

// ---------- elementwise add ----------
__global__ __launch_bounds__(256) void rt_add(const float* __restrict__ a,
                                              const float* __restrict__ b,
                                              float* __restrict__ o, int n4)
{
  int i = blockIdx.x * 256 + threadIdx.x;
  if (i < n4) {
    float4 x = ((const float4*)a)[i];
    float4 y = ((const float4*)b)[i];
    float4 z; z.x = x.x + y.x; z.y = x.y + y.y; z.z = x.z + y.z; z.w = x.w + y.w;
    ((float4*)o)[i] = z;
  }
}

// ---------- weight transpose+convert: W[K,N] f32 -> WT[Npad,K] bf16 ----------
__global__ __launch_bounds__(256) void rt_wt(const float* __restrict__ W,
                                             ushort16* __restrict__ WT,
                                             int K, int N, int Npad)
{
  __shared__ float t[32][33];
  int n0 = blockIdx.x * 32, k0 = blockIdx.y * 32;
  int c = threadIdx.x & 31, r = threadIdx.x >> 5;
#pragma unroll
  for (int i = 0; i < 4; i++) {
    int kk = k0 + r + i * 8;
    int nn = n0 + c;
    t[r + i * 8][c] = (nn < N) ? W[(size_t)kk * N + nn] : 0.f;
  }
  __syncthreads();
#pragma unroll
  for (int i = 0; i < 4; i++) {
    int nn = n0 + r + i * 8;
    int kk = k0 + c;
    if (nn < Npad) WT[(size_t)nn * K + kk] = f2bf(t[c][r + i * 8]);
  }
}

// ---------- Wval chunk-major convert: W[256][256] -> WC[(k/8)][col][8] bf16 ----------
__global__ __launch_bounds__(256) void rt_wc(const float* __restrict__ W,
                                             ushort16* __restrict__ WC)
{
  int gid = blockIdx.x * 256 + threadIdx.x;   // 8192 threads: (chunk 0..31, col 0..255)
  int c = gid >> 8, n = gid & 255;
  uint4 u;
  uint32 w0 = (uint32)f2bf(W[(c*8+0)*256 + n]) | ((uint32)f2bf(W[(c*8+1)*256 + n]) << 16);
  uint32 w1 = (uint32)f2bf(W[(c*8+2)*256 + n]) | ((uint32)f2bf(W[(c*8+3)*256 + n]) << 16);
  uint32 w2 = (uint32)f2bf(W[(c*8+4)*256 + n]) | ((uint32)f2bf(W[(c*8+5)*256 + n]) << 16);
  uint32 w3 = (uint32)f2bf(W[(c*8+6)*256 + n]) | ((uint32)f2bf(W[(c*8+7)*256 + n]) << 16);
  u.x = w0; u.y = w1; u.z = w2; u.w = w3;
  *(uint4*)&WC[(size_t)c * 2048 + n * 8] = u;
}

// ---------- value GEMM: no LDS, no barriers. A->regs, B from L2 (chunk-major) ----------
// Block = 128 rows x 256 cols, 8 waves; wave owns 16 rows x 256 cols.
__global__ __launch_bounds__(512, 2) void rt_vgemm(
    const float* __restrict__ A, const ushort16* __restrict__ BC,
    const float* __restrict__ bias, ushort16* __restrict__ Vout, int K)
{
  const int tid = threadIdx.x;
  const int lane = tid & 63, w = tid >> 6;
  const int l15 = lane & 15, l4 = lane >> 4;
  const int bm = blockIdx.x * 128;
  const int arow = bm + w * 16 + l15;

  const float* Ap = A + (size_t)arow * K + l4 * 8;

  f32x4 acc[16];
#pragma unroll
  for (int i = 0; i < 16; i++) acc[i] = (f32x4){0.f, 0.f, 0.f, 0.f};

  f32x4 a0 = *(const f32x4*)(Ap);
  f32x4 a1 = *(const f32x4*)(Ap + 4);

  for (int t = 0; t < 8; ++t) {
    f32x4 n0, n1;
    if (t < 7) {
      n0 = *(const f32x4*)(Ap + (t + 1) * 32);
      n1 = *(const f32x4*)(Ap + (t + 1) * 32 + 4);
    }
    uint4 u;
    u.x = cvtpk(a0[0], a0[1]); u.y = cvtpk(a0[2], a0[3]);
    u.z = cvtpk(a1[0], a1[1]); u.w = cvtpk(a1[2], a1[3]);
    bfx8 af = __builtin_bit_cast(bfx8, u);
    const ushort16* bp = BC + (size_t)(t * 4 + l4) * 2048 + l15 * 8;
#pragma unroll
    for (int ni = 0; ni < 16; ++ni) {
      bfx8 bg = *(const bfx8*)(const void*)(bp + ni * 128);
      acc[ni] = __builtin_amdgcn_mfma_f32_16x16x32_bf16(af, bg, acc[ni], 0, 0, 0);
    }
    a0 = n0; a1 = n1;
  }

  // epilogue: rows bm + w*16 + l4*4 + r, cols ni*16 + l15
  const int orow = bm + w * 16 + l4 * 4;
#pragma unroll
  for (int ni = 0; ni < 16; ++ni) {
    int col = ni * 16 + l15;
    float bv = bias[col];
    int hh = col >> 5, hd = col & 31;
#pragma unroll
    for (int r = 0; r < 4; ++r) {
      int row = orow + r;
      int bb = row / S_, s = row - bb * S_;
      Vout[(((size_t)bb * H_ + hh) * S_ + s) * HD_ + hd] = f2bf(acc[ni][r] + bv);
    }
  }
}

// ---------- MFMA bf16 GEMM (generic) ----------
#define GBM 128
#define GBN 128
#define GBK 32
#define LDP 40

__global__ __launch_bounds__(256) void rt_mgemm(
    const float* __restrict__ A, const ushort16* __restrict__ BT,
    const float* __restrict__ bias, float* __restrict__ C,
    ushort16* __restrict__ Sc,
    int M, int N, int K, float scale, int mode)
{
  __shared__ __align__(16) ushort16 As[GBM][LDP];
  __shared__ __align__(16) ushort16 Bs[GBN][LDP];
  const int tid  = threadIdx.x;
  const int lane = tid & 63;
  const int w    = tid >> 6;
  const int wr   = (w >> 1) * 64;
  const int wc   = (w & 1) * 64;
  const int bm   = blockIdx.y * GBM;
  const int bn   = blockIdx.x * GBN;
  const int l15  = lane & 15;
  const int l4   = lane >> 4;

  f32x4 acc[4][4];
#pragma unroll
  for (int i = 0; i < 4; i++)
#pragma unroll
    for (int j = 0; j < 4; j++)
      acc[i][j] = (f32x4){0.f, 0.f, 0.f, 0.f};

  const int arow = tid >> 3, akc = tid & 7;
  const int brow = tid >> 2, bkc = tid & 3;

  for (int k0 = 0; k0 < K; k0 += GBK) {
#pragma unroll
    for (int i = 0; i < 4; i++) {
      int row = arow + i * 32;
      f32x4 v = *(const f32x4*)(A + (size_t)(bm + row) * K + k0 + akc * 4);
      uint2 u;
      u.x = (uint32)f2bf(v.x) | ((uint32)f2bf(v.y) << 16);
      u.y = (uint32)f2bf(v.z) | ((uint32)f2bf(v.w) << 16);
      *(uint2*)(&As[row][akc * 4]) = u;
    }
#pragma unroll
    for (int i = 0; i < 2; i++) {
      int row = brow + i * 64;
      uint4 v = *(const uint4*)(BT + (size_t)(bn + row) * K + k0 + bkc * 8);
      *(uint4*)(&Bs[row][bkc * 8]) = v;
    }
    __syncthreads();

    bfx8 af[4], bg[4];
#pragma unroll
    for (int mi = 0; mi < 4; mi++)
      af[mi] = *(const bfx8*)(&As[wr + mi * 16 + l15][l4 * 8]);
#pragma unroll
    for (int ni = 0; ni < 4; ni++)
      bg[ni] = *(const bfx8*)(&Bs[wc + ni * 16 + l15][l4 * 8]);
#pragma unroll
    for (int mi = 0; mi < 4; mi++)
#pragma unroll
      for (int ni = 0; ni < 4; ni++)
        acc[mi][ni] = __builtin_amdgcn_mfma_f32_16x16x32_bf16(af[mi], bg[ni], acc[mi][ni], 0, 0, 0);
    __syncthreads();
  }

#pragma unroll
  for (int mi = 0; mi < 4; mi++) {
#pragma unroll
    for (int ni = 0; ni < 4; ni++) {
      int col = bn + wc + ni * 16 + l15;
      if (col >= N) continue;
      float bv = bias[col];
#pragma unroll
      for (int r = 0; r < 4; r++) {
        int row = bm + wr + mi * 16 + l4 * 4 + r;
        float vv = (acc[mi][ni][r] + bv) * scale;
        if (mode == 1) vv = fmaxf(vv, 0.f);
        if (mode == 2) {
          int bb = row / S_, s = row - bb * S_;
          int hh = col >> 5, hd = col & 31;
          Sc[(((size_t)bb * H_ + hh) * S_ + s) * HD_ + hd] = f2bf(vv);
        } else if (mode == 3) {
          int bb = row / NQ_, q = row - bb * NQ_;
          int hh = col >> 5, hd = col & 31;
          Sc[(((size_t)bb * H_ + hh) * NQP + q) * HD_ + hd] = f2bf(vv);
        } else {
          C[(size_t)row * N + col] = vv;
        }
      }
    }
  }
}

// ---------- V transpose per (b,h) ----------
__global__ __launch_bounds__(256) void rt_vtr(const ushort16* __restrict__ vh,
                                              ushort16* __restrict__ vt)
{
  __shared__ ushort16 t[64][33];
  int bh = blockIdx.x;
  const ushort16* src = vh + (size_t)bh * NQP * HD_;
  ushort16* dst = vt + (size_t)bh * HD_ * NQP;
  int tid = threadIdx.x;
  int lrow = tid >> 2, lc8 = (tid & 3) * 8;
  int ohd = tid >> 3, oq8 = (tid & 7) * 8;
  for (int r0 = 0; r0 < NQP; r0 += 64) {
    uint4 v = *(const uint4*)(src + (size_t)(r0 + lrow) * HD_ + lc8);
    ushort16* tp = &t[lrow][lc8];
    tp[0] = (ushort16)(v.x & 0xffff); tp[1] = (ushort16)(v.x >> 16);
    tp[2] = (ushort16)(v.y & 0xffff); tp[3] = (ushort16)(v.y >> 16);
    tp[4] = (ushort16)(v.z & 0xffff); tp[5] = (ushort16)(v.z >> 16);
    tp[6] = (ushort16)(v.w & 0xffff); tp[7] = (ushort16)(v.w >> 16);
    __syncthreads();
    uint4 o;
    o.x = (uint32)t[oq8 + 0][ohd] | ((uint32)t[oq8 + 1][ohd] << 16);
    o.y = (uint32)t[oq8 + 2][ohd] | ((uint32)t[oq8 + 3][ohd] << 16);
    o.z = (uint32)t[oq8 + 4][ohd] | ((uint32)t[oq8 + 5][ohd] << 16);
    o.w = (uint32)t[oq8 + 6][ohd] | ((uint32)t[oq8 + 7][ohd] << 16);
    *(uint4*)(dst + (size_t)ohd * NQP + r0 + oq8) = o;
    __syncthreads();
  }
}

// ---------- MFMA flash self-attention ----------
__global__ __launch_bounds__(256) void rt_fattn(
    const ushort16* __restrict__ qh, const ushort16* __restrict__ kh,
    const ushort16* __restrict__ vt, float* __restrict__ O)
{
  int gw  = blockIdx.x * 4 + (threadIdx.x >> 6);
  int bh  = gw / NQT, qt = gw - bh * NQT;
  int b   = bh >> 3, h = bh & 7;
  int lane = threadIdx.x & 63;
  int l15 = lane & 15, l4 = lane >> 4;
  int kb4 = l4 * 4;
  const ushort16* Qb = qh + (size_t)bh * NQP * HD_;
  const ushort16* Kb = kh + (size_t)bh * NQP * HD_;
  const ushort16* Vb = vt + (size_t)bh * HD_ * NQP;
  int q = qt * 16 + l15;

  bfx8 bgQ = *(const bfx8*)(const void*)(Qb + (size_t)q * HD_ + l4 * 8);
  f32x4 o0 = {0.f,0.f,0.f,0.f}, o1 = {0.f,0.f,0.f,0.f};
  float m = -1e30f, ssum = 0.f;

  for (int k0 = 0; k0 < NQP; k0 += 32) {
    bfx8 afk0 = *(const bfx8*)(const void*)(Kb + (size_t)(k0 + l15) * HD_ + l4 * 8);
    bfx8 afk1 = *(const bfx8*)(const void*)(Kb + (size_t)(k0 + 16 + l15) * HD_ + l4 * 8);
    f32x4 z = {0.f,0.f,0.f,0.f};
    f32x4 s0 = __builtin_amdgcn_mfma_f32_16x16x32_bf16(afk0, bgQ, z, 0, 0, 0);
    f32x4 s1 = __builtin_amdgcn_mfma_f32_16x16x32_bf16(afk1, bgQ, z, 0, 0, 0);
    int ka = k0 + kb4, kbb = k0 + 16 + kb4;
#pragma unroll
    for (int r = 0; r < 4; r++) {
      if (ka  + r >= NQ_) s0[r] = -1e30f;
      if (kbb + r >= NQ_) s1[r] = -1e30f;
    }
    float cm = fmaxf(fmaxf(fmaxf(s0[0], s0[1]), fmaxf(s0[2], s0[3])),
                     fmaxf(fmaxf(s1[0], s1[1]), fmaxf(s1[2], s1[3])));
    cm = fmaxf(cm, __shfl_xor(cm, 16));
    cm = fmaxf(cm, __shfl_xor(cm, 32));
    float nm = fmaxf(m, cm);
    float sc = __expf(m - nm);
    m = nm;
    f32x4 p0, p1;
#pragma unroll
    for (int r = 0; r < 4; r++) { p0[r] = __expf(s0[r] - m); p1[r] = __expf(s1[r] - m); }
    float ls = (p0[0]+p0[1]+p0[2]+p0[3]) + (p1[0]+p1[1]+p1[2]+p1[3]);
    ls += __shfl_xor(ls, 16);
    ls += __shfl_xor(ls, 32);
    ssum = ssum * sc + ls;

    uint32 t0w0 = cvtpk(p0[0], p0[1]);
    uint32 t0w1 = cvtpk(p0[2], p0[3]);
    uint32 t1w0 = cvtpk(p1[0], p1[1]);
    uint32 t1w1 = cvtpk(p1[2], p1[3]);
    int srcA = l15 + 32 * (l4 & 1);
    int srcB = srcA + 16;
    uint32 a00 = __shfl((int)t0w0, srcA), a01 = __shfl((int)t0w1, srcA);
    uint32 b00 = __shfl((int)t0w0, srcB), b01 = __shfl((int)t0w1, srcB);
    uint32 a10 = __shfl((int)t1w0, srcA), a11 = __shfl((int)t1w1, srcA);
    uint32 b10 = __shfl((int)t1w0, srcB), b11 = __shfl((int)t1w1, srcB);
    bool hi = (l4 >= 2);
    uint4 pw;
    pw.x = hi ? a10 : a00;
    pw.y = hi ? a11 : a01;
    pw.z = hi ? b10 : b00;
    pw.w = hi ? b11 : b01;
    bfx8 bgP = __builtin_bit_cast(bfx8, pw);

    bfx8 afv0 = *(const bfx8*)(const void*)(Vb + (size_t)l15 * NQP + k0 + l4 * 8);
    bfx8 afv1 = *(const bfx8*)(const void*)(Vb + (size_t)(16 + l15) * NQP + k0 + l4 * 8);
#pragma unroll
    for (int r = 0; r < 4; r++) { o0[r] *= sc; o1[r] *= sc; }
    o0 = __builtin_amdgcn_mfma_f32_16x16x32_bf16(afv0, bgP, o0, 0, 0, 0);
    o1 = __builtin_amdgcn_mfma_f32_16x16x32_bf16(afv1, bgP, o1, 0, 0, 0);
  }

  if (q < NQ_) {
    float inv = 1.f / ssum;
    float* op = O + ((size_t)(b * NQ_ + q)) * D_ + h * HD_ + kb4;
    f32x4 r0, r1;
#pragma unroll
    for (int r = 0; r < 4; r++) { r0[r] = o0[r] * inv; r1[r] = o1[r] * inv; }
    *(f32x4*)op = r0;
    *(f32x4*)(op + 16) = r1;
  }
}

// ---------- LayerNorm ----------
__global__ __launch_bounds__(256) void rt_ln(
    const float* __restrict__ X, const float* __restrict__ R,
    const float* __restrict__ g, const float* __restrict__ be,
    float* __restrict__ O, int rows)
{
  int row = blockIdx.x * 4 + (threadIdx.x >> 6);
  int lane = threadIdx.x & 63;
  if (row >= rows) return;
  size_t base = (size_t)row * D_ + lane * 4;
  float4 x = *(const float4*)(X + base);
  float4 r = *(const float4*)(R + base);
  float v0 = x.x + r.x, v1 = x.y + r.y, v2 = x.z + r.z, v3 = x.w + r.w;
  float s = v0 + v1 + v2 + v3;
  float sq = v0*v0 + v1*v1 + v2*v2 + v3*v3;
#pragma unroll
  for (int o = 32; o >= 1; o >>= 1) { s += __shfl_xor(s, o); sq += __shfl_xor(sq, o); }
  float mean = s * (1.f / D_);
  float var  = sq * (1.f / D_) - mean * mean;
  float inv  = 1.f / sqrtf(var + 1e-5f);
  int c = lane * 4;
  float4 gv = *(const float4*)(g + c);
  float4 bv = *(const float4*)(be + c);
  float4 o4;
  o4.x = (v0 - mean) * inv * gv.x + bv.x;
  o4.y = (v1 - mean) * inv * gv.y + bv.y;
  o4.z = (v2 - mean) * inv * gv.z + bv.z;
  o4.w = (v3 - mean) * inv * gv.w + bv.w;
  *(float4*)(O + base) = o4;
}

// ---------- attention-weight softmax ----------
__global__ __launch_bounds__(256) void rt_awsm(float* __restrict__ aw, int groups)
{
  int gidx = blockIdx.x * 256 + threadIdx.x;
  if (gidx >= groups) return;
  float* p = aw + (size_t)gidx * 12;
  float e[12]; float m = -1e30f;
#pragma unroll
  for (int i = 0; i < 12; i++) { e[i] = p[i]; m = fmaxf(m, e[i]); }
  float s = 0.f;
#pragma unroll
  for (int i = 0; i < 12; i++) { e[i] = __expf(e[i] - m); s += e[i]; }
  float inv = 1.f / s;
#pragma unroll
  for (int i = 0; i < 12; i++) p[i] = e[i] * inv;
}

// ---------- deformable sampling: thread = (b,q,h, hd-octet) ----------
__device__ inline void rt_acc8(const ushort16* p, float wgt, float* acc) {
  uint4 v = *(const uint4*)(const void*)p;
  acc[0] += wgt * __uint_as_float(v.x << 16);
  acc[1] += wgt * __uint_as_float(v.x & 0xffff0000u);
  acc[2] += wgt * __uint_as_float(v.y << 16);
  acc[3] += wgt * __uint_as_float(v.y & 0xffff0000u);
  acc[4] += wgt * __uint_as_float(v.z << 16);
  acc[5] += wgt * __uint_as_float(v.z & 0xffff0000u);
  acc[6] += wgt * __uint_as_float(v.w << 16);
  acc[7] += wgt * __uint_as_float(v.w & 0xffff0000u);
}

__global__ __launch_bounds__(256) void rt_deform(
    const ushort16* __restrict__ value,
    const float* __restrict__ off,
    const float* __restrict__ aw,
    const float* __restrict__ ref,
    float* __restrict__ O)
{
  int gid = blockIdx.x * 256 + threadIdx.x;
  int hd0 = (gid & 3) * 8;
  int bqh = gid >> 2;
  int h   = bqh & 7;
  int bq  = bqh >> 3;
  int b   = bq / NQ_;
  const float* rp = ref + (size_t)bq * 4;
  float rx = rp[0], ry = rp[1];
  float rw = rp[2] * 0.125f, rh = rp[3] * 0.125f;
  const float* op = off + (size_t)bqh * 24;
  const float* ap = aw  + (size_t)bqh * 12;
  const ushort16* vb = value + ((size_t)b * H_ + h) * (size_t)S_ * HD_ + hd0;
  float acc[8];
#pragma unroll
  for (int i = 0; i < 8; i++) acc[i] = 0.f;
  const int starts[3] = {0, 6400, 8000};
  const int dims[3]   = {80, 40, 20};
#pragma unroll
  for (int l = 0; l < L_; l++) {
    const int Wl = dims[l];
    const ushort16* vl = vb + (size_t)starts[l] * HD_;
#pragma unroll
    for (int p = 0; p < P_; p++) {
      int ip = l * P_ + p;
      float w = ap[ip];
      float x = (rx + op[ip*2+0] * rw) * Wl - 0.5f;
      float y = (ry + op[ip*2+1] * rh) * Wl - 0.5f;
      float x0f = floorf(x), y0f = floorf(y);
      int   x0 = (int)x0f,  y0 = (int)y0f;
      float wx1 = x - x0f, wy1 = y - y0f;
      float wx0 = 1.f - wx1, wy0 = 1.f - wy1;
      bool xok0 = (x0 >= 0) & (x0 < Wl), xok1 = (x0+1 >= 0) & (x0+1 < Wl);
      bool yok0 = (y0 >= 0) & (y0 < Wl), yok1 = (y0+1 >= 0) & (y0+1 < Wl);
      const ushort16* r0p = vl + (size_t)(y0 * Wl) * HD_;
      const ushort16* r1p = r0p + (size_t)Wl * HD_;
      if (xok0 & yok0) rt_acc8(r0p + (size_t)x0 * HD_,     w * wx0 * wy0, acc);
      if (xok1 & yok0) rt_acc8(r0p + (size_t)(x0+1) * HD_, w * wx1 * wy0, acc);
      if (xok0 & yok1) rt_acc8(r1p + (size_t)x0 * HD_,     w * wx0 * wy1, acc);
      if (xok1 & yok1) rt_acc8(r1p + (size_t)(x0+1) * HD_, w * wx1 * wy1, acc);
    }
  }
  float* outp = O + (size_t)bq * D_ + h * HD_ + hd0;
  float4 a0, a1;
  a0.x = acc[0]; a0.y = acc[1]; a0.z = acc[2]; a0.w = acc[3];
  a1.x = acc[4]; a1.y = acc[5]; a1.z = acc[6]; a1.w = acc[7];
  *(float4*)outp = a0;
  *(float4*)(outp + 4) = a1;
}

// ---------- launch ----------
extern "C" void kernel_launch(void* const* d_in, const int* in_sizes, int n_in,
                              void* d_out, int out_size, void* d_ws, size_t ws_size,
                              hipStream_t stream)
{
  const float* hs   = (const float*)d_in[0];
  const float* pos  = (const float*)d_in[1];
  const float* ref  = (const float*)d_in[2];
  const float* ehs  = (const float*)d_in[3];
  const float* Wq   = (const float*)d_in[4];
  const float* Wk   = (const float*)d_in[5];
  const float* Wv   = (const float*)d_in[6];
  const float* Wo   = (const float*)d_in[7];
  const float* Woff = (const float*)d_in[8];
  const float* Waw  = (const float*)d_in[9];
  const float* Wval = (const float*)d_in[10];
  const float* Wout = (const float*)d_in[11];
  const float* W1   = (const float*)d_in[12];
  const float* W2   = (const float*)d_in[13];
  const float* bq   = (const float*)d_in[14];
  const float* bk   = (const float*)d_in[15];
  const float* bvv  = (const float*)d_in[16];
  const float* bo   = (const float*)d_in[17];
  const float* boff = (const float*)d_in[18];
  const float* baw  = (const float*)d_in[19];
  const float* bval = (const float*)d_in[20];
  const float* bout = (const float*)d_in[21];
  const float* b1   = (const float*)d_in[22];
  const float* b2   = (const float*)d_in[23];
  const float* ln1g = (const float*)d_in[24];
  const float* ln1b = (const float*)d_in[25];
  const float* ln2g = (const float*)d_in[26];
  const float* ln2b = (const float*)d_in[27];
  const float* ln3g = (const float*)d_in[28];
  const float* ln3b = (const float*)d_in[29];
  float* out = (float*)d_out;

  float* ws = (float*)d_ws;
  ushort16* value = (ushort16*)ws;
  float* hp   = ws + 34406400;
  float* t0   = ws + 36864000;
  float* t1   = ws + 39321600;
  float* hs1  = ws + 41779200;
  float* hs2  = ws + 44236800;
  float* offb = ws + 46694400;
  float* awb  = ws + 48537600;
  float* ffn1 = ws + 49459200;
  ushort16* qh = (ushort16*)(ws + 59289600);
  ushort16* kh = (ushort16*)(ws + 60600320);
  ushort16* vh = (ushort16*)(ws + 61911040);
  ushort16* vt = (ushort16*)(ws + 63221760);
  ushort16* wbase = (ushort16*)(ws + 64532480);
  ushort16* WqT   = wbase;
  ushort16* WkT   = WqT   + 65536;
  ushort16* WvT   = WkT   + 65536;
  ushort16* WoT   = WvT   + 65536;
  ushort16* WoffT = WoT   + 65536;
  ushort16* WawT  = WoffT + 65536;
  ushort16* WvalC = WawT  + 32768;   // chunk-major [k/8][col][8] bf16
  ushort16* WoutT = WvalC + 65536;
  ushort16* W1T   = WoutT + 65536;
  ushort16* W2T   = W1T   + 262144;

  const float qscale = 0.17677669529663687f;

  rt_wt<<<dim3(8, 8),  256, 0, stream>>>(Wq,   WqT,   256, 256, 256);
  rt_wt<<<dim3(8, 8),  256, 0, stream>>>(Wk,   WkT,   256, 256, 256);
  rt_wt<<<dim3(8, 8),  256, 0, stream>>>(Wv,   WvT,   256, 256, 256);
  rt_wt<<<dim3(8, 8),  256, 0, stream>>>(Wo,   WoT,   256, 256, 256);
  rt_wt<<<dim3(8, 8),  256, 0, stream>>>(Woff, WoffT, 256, 192, 256);
  rt_wt<<<dim3(4, 8),  256, 0, stream>>>(Waw,  WawT,  256,  96, 128);
  rt_wc<<<dim3(32),    256, 0, stream>>>(Wval, WvalC);
  rt_wt<<<dim3(8, 8),  256, 0, stream>>>(Wout, WoutT, 256, 256, 256);
  rt_wt<<<dim3(32, 8), 256, 0, stream>>>(W1,   W1T,   256, 1024, 1024);
  rt_wt<<<dim3(8, 32), 256, 0, stream>>>(W2,   W2T,   1024, 256, 256);

  // value projection: barrier-free, LDS-free streaming GEMM
  rt_vgemm<<<dim3(MV/128), 512, 0, stream>>>(ehs, WvalC, bval, value, D_);

  rt_add<<<dim3(M1*D_/4/256), 256, 0, stream>>>(hs, pos, hp, M1*D_/4);
  rt_mgemm<<<dim3(2, M1/GBM), 256, 0, stream>>>(hp, WqT, bq,  nullptr, qh, M1, D_, D_, qscale, 3);
  rt_mgemm<<<dim3(2, M1/GBM), 256, 0, stream>>>(hp, WkT, bk,  nullptr, kh, M1, D_, D_, 1.f, 3);
  rt_mgemm<<<dim3(2, M1/GBM), 256, 0, stream>>>(hs, WvT, bvv, nullptr, vh, M1, D_, D_, 1.f, 3);
  rt_vtr<<<dim3(B_*H_), 256, 0, stream>>>(vh, vt);
  rt_fattn<<<dim3(B_*H_*NQT/4), 256, 0, stream>>>(qh, kh, vt, t0);
  rt_mgemm<<<dim3(2, M1/GBM), 256, 0, stream>>>(t0, WoT, bo, t1, nullptr, M1, D_, D_, 1.f, 0);
  rt_ln<<<dim3(M1/4), 256, 0, stream>>>(hs, t1, ln1g, ln1b, hs1, M1);
  rt_add<<<dim3(M1*D_/4/256), 256, 0, stream>>>(hs1, pos, hp, M1*D_/4);
  rt_mgemm<<<dim3(2, M1/GBM), 256, 0, stream>>>(hp, WoffT, boff, offb, nullptr, M1, 192, D_, 1.f, 0);
  rt_mgemm<<<dim3(1, M1/GBM), 256, 0, stream>>>(hp, WawT,  baw,  awb,  nullptr, M1,  96, D_, 1.f, 0);
  rt_awsm<<<dim3(B_*NQ_*H_/256), 256, 0, stream>>>(awb, B_*NQ_*H_);
  rt_deform<<<dim3(M1*H_*4/256), 256, 0, stream>>>(value, offb, awb, ref, t0);
  rt_mgemm<<<dim3(2, M1/GBM), 256, 0, stream>>>(t0, WoutT, bout, t1, nullptr, M1, D_, D_, 1.f, 0);
  rt_ln<<<dim3(M1/4), 256, 0, stream>>>(hs1, t1, ln2g, ln2b, hs2, M1);
  rt_mgemm<<<dim3(8, M1/GBM), 256, 0, stream>>>(hs2, W1T, b1, ffn1, nullptr, M1, FFN_, D_, 1.f, 1);
  rt_mgemm<<<dim3(2, M1/GBM), 256, 0, stream>>>(ffn1, W2T, b2, t1, nullptr, M1, D_, FFN_, 1.f, 0);
  rt_ln<<<dim3(M1/4), 256, 0, stream>>>(hs2, t1, ln3g, ln3b, out, M1);
}

// Round 7
// 466.821 us; speedup vs baseline: 1.0835x; 1.0835x over previous
//
#include <hip/hip_runtime.h>
#include <hip/hip_bf16.h>

typedef unsigned int  uint32;
typedef unsigned short ushort16;
typedef __bf16 bfx8 __attribute__((ext_vector_type(8)));
typedef float  f32x4 __attribute__((ext_vector_type(4)));

typedef __attribute__((address_space(1))) const unsigned int gas_u32;
typedef __attribute__((address_space(3))) unsigned int las_u32;

#define B_   32
#define NQ_  300
#define D_   256
#define H_   8
#define HD_  32
#define L_   3
#define P_   4
#define S_   8400
#define FFN_ 1024
#define M1   (B_*NQ_)    // 9600
#define MV   (B_*S_)     // 268800
#define NQP  320
#define NQT  19

// ---------- helpers ----------
__device__ inline ushort16 f2bf(float x) {
  uint32 u = __float_as_uint(x);
  uint32 r = u + 0x7fffu + ((u >> 16) & 1u);
  return (ushort16)(r >> 16);
}
__device__ inline float bf2f(ushort16 v) {
  return __uint_as_float(((uint32)v) << 16);
}
__device__ inline uint32 cvtpk(float lo, float hi) {
  uint32 r; asm("v_cvt_pk_bf16_f32 %0, %1, %2" : "=v"(r) : "v"(lo), "v"(hi)); return r;
}

// ---------- elementwise add ----------
__global__ __launch_bounds__(256) void rt_add(const float* __restrict__ a,
                                              const float* __restrict__ b,
                                              float* __restrict__ o, int n4)
{
  int i = blockIdx.x * 256 + threadIdx.x;
  if (i < n4) {
    float4 x = ((const float4*)a)[i];
    float4 y = ((const float4*)b)[i];
    float4 z; z.x = x.x + y.x; z.y = x.y + y.y; z.z = x.z + y.z; z.w = x.w + y.w;
    ((float4*)o)[i] = z;
  }
}

// ---------- weight transpose+convert: W[K,N] f32 -> WT[Npad,K] bf16 ----------
__global__ __launch_bounds__(256) void rt_wt(const float* __restrict__ W,
                                             ushort16* __restrict__ WT,
                                             int K, int N, int Npad)
{
  __shared__ float t[32][33];
  int n0 = blockIdx.x * 32, k0 = blockIdx.y * 32;
  int c = threadIdx.x & 31, r = threadIdx.x >> 5;
#pragma unroll
  for (int i = 0; i < 4; i++) {
    int kk = k0 + r + i * 8;
    int nn = n0 + c;
    t[r + i * 8][c] = (nn < N) ? W[(size_t)kk * N + nn] : 0.f;
  }
  __syncthreads();
#pragma unroll
  for (int i = 0; i < 4; i++) {
    int nn = n0 + r + i * 8;
    int kk = k0 + c;
    if (nn < Npad) WT[(size_t)nn * K + kk] = f2bf(t[c][r + i * 8]);
  }
}

// ---------- Wval chunk-major convert: W[256][256] -> WC[(k/8)][col][8] bf16 ----------
__global__ __launch_bounds__(256) void rt_wc(const float* __restrict__ W,
                                             ushort16* __restrict__ WC)
{
  int gid = blockIdx.x * 256 + threadIdx.x;   // 8192 threads: (chunk 0..31, col 0..255)
  int c = gid >> 8, n = gid & 255;
  uint4 u;
  uint32 w0 = (uint32)f2bf(W[(c*8+0)*256 + n]) | ((uint32)f2bf(W[(c*8+1)*256 + n]) << 16);
  uint32 w1 = (uint32)f2bf(W[(c*8+2)*256 + n]) | ((uint32)f2bf(W[(c*8+3)*256 + n]) << 16);
  uint32 w2 = (uint32)f2bf(W[(c*8+4)*256 + n]) | ((uint32)f2bf(W[(c*8+5)*256 + n]) << 16);
  uint32 w3 = (uint32)f2bf(W[(c*8+6)*256 + n]) | ((uint32)f2bf(W[(c*8+7)*256 + n]) << 16);
  u.x = w0; u.y = w1; u.z = w2; u.w = w3;
  *(uint4*)&WC[(size_t)c * 2048 + n * 8] = u;
}

// ---------- value GEMM: whole B (128KB) staged once in LDS; barrier-free K-loop ----------
// Block = 256 rows x 256 cols, 1024 threads / 16 waves; wave = 16 rows x 256 cols.
__global__ __launch_bounds__(1024, 1) void rt_vgemm(
    const float* __restrict__ A, const ushort16* __restrict__ BC,
    const float* __restrict__ bias, ushort16* __restrict__ Vout)
{
  __shared__ __align__(16) char ldsB[131072];
  const int tid = threadIdx.x;
  const int lane = tid & 63, w = tid >> 6;
  const int l15 = lane & 15, l4 = lane >> 4;
  const int bm = blockIdx.x * 256;
  const int arow = bm + w * 16 + l15;
  const float* Ap = A + (size_t)arow * 256 + l4 * 8;

  // stage all of B linearly (layout already chunk-major: [c][n][8] -> c*4096 + n*16 bytes)
#pragma unroll
  for (int i = 0; i < 8; ++i)
    __builtin_amdgcn_global_load_lds(
        (gas_u32*)(const void*)((const char*)BC + tid * 16 + i * 16384),
        (las_u32*)(void*)(&ldsB[tid * 16 + i * 16384]), 16, 0, 0);

  // depth-2 A prefetch (t=0, t=1)
  f32x4 aA = *(const f32x4*)(Ap +  0);
  f32x4 aB = *(const f32x4*)(Ap +  4);
  f32x4 aC = *(const f32x4*)(Ap + 32);
  f32x4 aD = *(const f32x4*)(Ap + 36);

  f32x4 acc[16];
#pragma unroll
  for (int i = 0; i < 16; ++i) acc[i] = (f32x4){0.f, 0.f, 0.f, 0.f};

  __syncthreads();   // one-time drain: B staged, first A in regs

#pragma unroll
  for (int tt = 0; tt < 4; ++tt) {
    {
      const int t = 2 * tt;
      uint4 u;
      u.x = cvtpk(aA[0], aA[1]); u.y = cvtpk(aA[2], aA[3]);
      u.z = cvtpk(aB[0], aB[1]); u.w = cvtpk(aB[2], aB[3]);
      bfx8 af = __builtin_bit_cast(bfx8, u);
      if (tt < 3) {
        aA = *(const f32x4*)(Ap + (t + 2) * 32);
        aB = *(const f32x4*)(Ap + (t + 2) * 32 + 4);
      }
      const char* bp = &ldsB[(t * 4 + l4) * 4096 + l15 * 16];
#pragma unroll
      for (int ni = 0; ni < 16; ++ni) {
        bfx8 bg = *(const bfx8*)(const void*)(bp + ni * 256);
        acc[ni] = __builtin_amdgcn_mfma_f32_16x16x32_bf16(af, bg, acc[ni], 0, 0, 0);
      }
    }
    {
      const int t = 2 * tt + 1;
      uint4 u;
      u.x = cvtpk(aC[0], aC[1]); u.y = cvtpk(aC[2], aC[3]);
      u.z = cvtpk(aD[0], aD[1]); u.w = cvtpk(aD[2], aD[3]);
      bfx8 af = __builtin_bit_cast(bfx8, u);
      if (tt < 3) {
        aC = *(const f32x4*)(Ap + (t + 2) * 32);
        aD = *(const f32x4*)(Ap + (t + 2) * 32 + 4);
      }
      const char* bp = &ldsB[(t * 4 + l4) * 4096 + l15 * 16];
#pragma unroll
      for (int ni = 0; ni < 16; ++ni) {
        bfx8 bg = *(const bfx8*)(const void*)(bp + ni * 256);
        acc[ni] = __builtin_amdgcn_mfma_f32_16x16x32_bf16(af, bg, acc[ni], 0, 0, 0);
      }
    }
  }

  const int orow = bm + w * 16 + l4 * 4;
#pragma unroll
  for (int ni = 0; ni < 16; ++ni) {
    int col = ni * 16 + l15;
    float bv = bias[col];
    int hh = col >> 5, hd = col & 31;
#pragma unroll
    for (int r = 0; r < 4; ++r) {
      int row = orow + r;
      int bb = row / S_, s = row - bb * S_;
      Vout[(((size_t)bb * H_ + hh) * S_ + s) * HD_ + hd] = f2bf(acc[ni][r] + bv);
    }
  }
}

// ---------- MFMA bf16 GEMM (generic) ----------
#define GBM 128
#define GBN 128
#define GBK 32
#define LDP 40

__global__ __launch_bounds__(256) void rt_mgemm(
    const float* __restrict__ A, const ushort16* __restrict__ BT,
    const float* __restrict__ bias, float* __restrict__ C,
    ushort16* __restrict__ Sc,
    int M, int N, int K, float scale, int mode)
{
  __shared__ __align__(16) ushort16 As[GBM][LDP];
  __shared__ __align__(16) ushort16 Bs[GBN][LDP];
  const int tid  = threadIdx.x;
  const int lane = tid & 63;
  const int w    = tid >> 6;
  const int wr   = (w >> 1) * 64;
  const int wc   = (w & 1) * 64;
  const int bm   = blockIdx.y * GBM;
  const int bn   = blockIdx.x * GBN;
  const int l15  = lane & 15;
  const int l4   = lane >> 4;

  f32x4 acc[4][4];
#pragma unroll
  for (int i = 0; i < 4; i++)
#pragma unroll
    for (int j = 0; j < 4; j++)
      acc[i][j] = (f32x4){0.f, 0.f, 0.f, 0.f};

  const int arow = tid >> 3, akc = tid & 7;
  const int brow = tid >> 2, bkc = tid & 3;

  for (int k0 = 0; k0 < K; k0 += GBK) {
#pragma unroll
    for (int i = 0; i < 4; i++) {
      int row = arow + i * 32;
      f32x4 v = *(const f32x4*)(A + (size_t)(bm + row) * K + k0 + akc * 4);
      uint2 u;
      u.x = (uint32)f2bf(v.x) | ((uint32)f2bf(v.y) << 16);
      u.y = (uint32)f2bf(v.z) | ((uint32)f2bf(v.w) << 16);
      *(uint2*)(&As[row][akc * 4]) = u;
    }
#pragma unroll
    for (int i = 0; i < 2; i++) {
      int row = brow + i * 64;
      uint4 v = *(const uint4*)(BT + (size_t)(bn + row) * K + k0 + bkc * 8);
      *(uint4*)(&Bs[row][bkc * 8]) = v;
    }
    __syncthreads();

    bfx8 af[4], bg[4];
#pragma unroll
    for (int mi = 0; mi < 4; mi++)
      af[mi] = *(const bfx8*)(&As[wr + mi * 16 + l15][l4 * 8]);
#pragma unroll
    for (int ni = 0; ni < 4; ni++)
      bg[ni] = *(const bfx8*)(&Bs[wc + ni * 16 + l15][l4 * 8]);
#pragma unroll
    for (int mi = 0; mi < 4; mi++)
#pragma unroll
      for (int ni = 0; ni < 4; ni++)
        acc[mi][ni] = __builtin_amdgcn_mfma_f32_16x16x32_bf16(af[mi], bg[ni], acc[mi][ni], 0, 0, 0);
    __syncthreads();
  }

#pragma unroll
  for (int mi = 0; mi < 4; mi++) {
#pragma unroll
    for (int ni = 0; ni < 4; ni++) {
      int col = bn + wc + ni * 16 + l15;
      if (col >= N) continue;
      float bv = bias[col];
#pragma unroll
      for (int r = 0; r < 4; r++) {
        int row = bm + wr + mi * 16 + l4 * 4 + r;
        float vv = (acc[mi][ni][r] + bv) * scale;
        if (mode == 1) vv = fmaxf(vv, 0.f);
        if (mode == 2) {
          int bb = row / S_, s = row - bb * S_;
          int hh = col >> 5, hd = col & 31;
          Sc[(((size_t)bb * H_ + hh) * S_ + s) * HD_ + hd] = f2bf(vv);
        } else if (mode == 3) {
          int bb = row / NQ_, q = row - bb * NQ_;
          int hh = col >> 5, hd = col & 31;
          Sc[(((size_t)bb * H_ + hh) * NQP + q) * HD_ + hd] = f2bf(vv);
        } else {
          C[(size_t)row * N + col] = vv;
        }
      }
    }
  }
}

// ---------- V transpose per (b,h) ----------
__global__ __launch_bounds__(256) void rt_vtr(const ushort16* __restrict__ vh,
                                              ushort16* __restrict__ vt)
{
  __shared__ ushort16 t[64][33];
  int bh = blockIdx.x;
  const ushort16* src = vh + (size_t)bh * NQP * HD_;
  ushort16* dst = vt + (size_t)bh * HD_ * NQP;
  int tid = threadIdx.x;
  int lrow = tid >> 2, lc8 = (tid & 3) * 8;
  int ohd = tid >> 3, oq8 = (tid & 7) * 8;
  for (int r0 = 0; r0 < NQP; r0 += 64) {
    uint4 v = *(const uint4*)(src + (size_t)(r0 + lrow) * HD_ + lc8);
    ushort16* tp = &t[lrow][lc8];
    tp[0] = (ushort16)(v.x & 0xffff); tp[1] = (ushort16)(v.x >> 16);
    tp[2] = (ushort16)(v.y & 0xffff); tp[3] = (ushort16)(v.y >> 16);
    tp[4] = (ushort16)(v.z & 0xffff); tp[5] = (ushort16)(v.z >> 16);
    tp[6] = (ushort16)(v.w & 0xffff); tp[7] = (ushort16)(v.w >> 16);
    __syncthreads();
    uint4 o;
    o.x = (uint32)t[oq8 + 0][ohd] | ((uint32)t[oq8 + 1][ohd] << 16);
    o.y = (uint32)t[oq8 + 2][ohd] | ((uint32)t[oq8 + 3][ohd] << 16);
    o.z = (uint32)t[oq8 + 4][ohd] | ((uint32)t[oq8 + 5][ohd] << 16);
    o.w = (uint32)t[oq8 + 6][ohd] | ((uint32)t[oq8 + 7][ohd] << 16);
    *(uint4*)(dst + (size_t)ohd * NQP + r0 + oq8) = o;
    __syncthreads();
  }
}

// ---------- MFMA flash self-attention ----------
__global__ __launch_bounds__(256) void rt_fattn(
    const ushort16* __restrict__ qh, const ushort16* __restrict__ kh,
    const ushort16* __restrict__ vt, float* __restrict__ O)
{
  int gw  = blockIdx.x * 4 + (threadIdx.x >> 6);
  int bh  = gw / NQT, qt = gw - bh * NQT;
  int b   = bh >> 3, h = bh & 7;
  int lane = threadIdx.x & 63;
  int l15 = lane & 15, l4 = lane >> 4;
  int kb4 = l4 * 4;
  const ushort16* Qb = qh + (size_t)bh * NQP * HD_;
  const ushort16* Kb = kh + (size_t)bh * NQP * HD_;
  const ushort16* Vb = vt + (size_t)bh * HD_ * NQP;
  int q = qt * 16 + l15;

  bfx8 bgQ = *(const bfx8*)(const void*)(Qb + (size_t)q * HD_ + l4 * 8);
  f32x4 o0 = {0.f,0.f,0.f,0.f}, o1 = {0.f,0.f,0.f,0.f};
  float m = -1e30f, ssum = 0.f;

  for (int k0 = 0; k0 < NQP; k0 += 32) {
    bfx8 afk0 = *(const bfx8*)(const void*)(Kb + (size_t)(k0 + l15) * HD_ + l4 * 8);
    bfx8 afk1 = *(const bfx8*)(const void*)(Kb + (size_t)(k0 + 16 + l15) * HD_ + l4 * 8);
    f32x4 z = {0.f,0.f,0.f,0.f};
    f32x4 s0 = __builtin_amdgcn_mfma_f32_16x16x32_bf16(afk0, bgQ, z, 0, 0, 0);
    f32x4 s1 = __builtin_amdgcn_mfma_f32_16x16x32_bf16(afk1, bgQ, z, 0, 0, 0);
    int ka = k0 + kb4, kbb = k0 + 16 + kb4;
#pragma unroll
    for (int r = 0; r < 4; r++) {
      if (ka  + r >= NQ_) s0[r] = -1e30f;
      if (kbb + r >= NQ_) s1[r] = -1e30f;
    }
    float cm = fmaxf(fmaxf(fmaxf(s0[0], s0[1]), fmaxf(s0[2], s0[3])),
                     fmaxf(fmaxf(s1[0], s1[1]), fmaxf(s1[2], s1[3])));
    cm = fmaxf(cm, __shfl_xor(cm, 16));
    cm = fmaxf(cm, __shfl_xor(cm, 32));
    float nm = fmaxf(m, cm);
    float sc = __expf(m - nm);
    m = nm;
    f32x4 p0, p1;
#pragma unroll
    for (int r = 0; r < 4; r++) { p0[r] = __expf(s0[r] - m); p1[r] = __expf(s1[r] - m); }
    float ls = (p0[0]+p0[1]+p0[2]+p0[3]) + (p1[0]+p1[1]+p1[2]+p1[3]);
    ls += __shfl_xor(ls, 16);
    ls += __shfl_xor(ls, 32);
    ssum = ssum * sc + ls;

    uint32 t0w0 = cvtpk(p0[0], p0[1]);
    uint32 t0w1 = cvtpk(p0[2], p0[3]);
    uint32 t1w0 = cvtpk(p1[0], p1[1]);
    uint32 t1w1 = cvtpk(p1[2], p1[3]);
    int srcA = l15 + 32 * (l4 & 1);
    int srcB = srcA + 16;
    uint32 a00 = __shfl((int)t0w0, srcA), a01 = __shfl((int)t0w1, srcA);
    uint32 b00 = __shfl((int)t0w0, srcB), b01 = __shfl((int)t0w1, srcB);
    uint32 a10 = __shfl((int)t1w0, srcA), a11 = __shfl((int)t1w1, srcA);
    uint32 b10 = __shfl((int)t1w0, srcB), b11 = __shfl((int)t1w1, srcB);
    bool hi = (l4 >= 2);
    uint4 pw;
    pw.x = hi ? a10 : a00;
    pw.y = hi ? a11 : a01;
    pw.z = hi ? b10 : b00;
    pw.w = hi ? b11 : b01;
    bfx8 bgP = __builtin_bit_cast(bfx8, pw);

    bfx8 afv0 = *(const bfx8*)(const void*)(Vb + (size_t)l15 * NQP + k0 + l4 * 8);
    bfx8 afv1 = *(const bfx8*)(const void*)(Vb + (size_t)(16 + l15) * NQP + k0 + l4 * 8);
#pragma unroll
    for (int r = 0; r < 4; r++) { o0[r] *= sc; o1[r] *= sc; }
    o0 = __builtin_amdgcn_mfma_f32_16x16x32_bf16(afv0, bgP, o0, 0, 0, 0);
    o1 = __builtin_amdgcn_mfma_f32_16x16x32_bf16(afv1, bgP, o1, 0, 0, 0);
  }

  if (q < NQ_) {
    float inv = 1.f / ssum;
    float* op = O + ((size_t)(b * NQ_ + q)) * D_ + h * HD_ + kb4;
    f32x4 r0, r1;
#pragma unroll
    for (int r = 0; r < 4; r++) { r0[r] = o0[r] * inv; r1[r] = o1[r] * inv; }
    *(f32x4*)op = r0;
    *(f32x4*)(op + 16) = r1;
  }
}

// ---------- LayerNorm ----------
__global__ __launch_bounds__(256) void rt_ln(
    const float* __restrict__ X, const float* __restrict__ R,
    const float* __restrict__ g, const float* __restrict__ be,
    float* __restrict__ O, int rows)
{
  int row = blockIdx.x * 4 + (threadIdx.x >> 6);
  int lane = threadIdx.x & 63;
  if (row >= rows) return;
  size_t base = (size_t)row * D_ + lane * 4;
  float4 x = *(const float4*)(X + base);
  float4 r = *(const float4*)(R + base);
  float v0 = x.x + r.x, v1 = x.y + r.y, v2 = x.z + r.z, v3 = x.w + r.w;
  float s = v0 + v1 + v2 + v3;
  float sq = v0*v0 + v1*v1 + v2*v2 + v3*v3;
#pragma unroll
  for (int o = 32; o >= 1; o >>= 1) { s += __shfl_xor(s, o); sq += __shfl_xor(sq, o); }
  float mean = s * (1.f / D_);
  float var  = sq * (1.f / D_) - mean * mean;
  float inv  = 1.f / sqrtf(var + 1e-5f);
  int c = lane * 4;
  float4 gv = *(const float4*)(g + c);
  float4 bv = *(const float4*)(be + c);
  float4 o4;
  o4.x = (v0 - mean) * inv * gv.x + bv.x;
  o4.y = (v1 - mean) * inv * gv.y + bv.y;
  o4.z = (v2 - mean) * inv * gv.z + bv.z;
  o4.w = (v3 - mean) * inv * gv.w + bv.w;
  *(float4*)(O + base) = o4;
}

// ---------- attention-weight softmax ----------
__global__ __launch_bounds__(256) void rt_awsm(float* __restrict__ aw, int groups)
{
  int gidx = blockIdx.x * 256 + threadIdx.x;
  if (gidx >= groups) return;
  float* p = aw + (size_t)gidx * 12;
  float e[12]; float m = -1e30f;
#pragma unroll
  for (int i = 0; i < 12; i++) { e[i] = p[i]; m = fmaxf(m, e[i]); }
  float s = 0.f;
#pragma unroll
  for (int i = 0; i < 12; i++) { e[i] = __expf(e[i] - m); s += e[i]; }
  float inv = 1.f / s;
#pragma unroll
  for (int i = 0; i < 12; i++) p[i] = e[i] * inv;
}

// ---------- deformable sampling: thread = (b,q,h, hd-octet) ----------
__device__ inline void rt_acc8(const ushort16* p, float wgt, float* acc) {
  uint4 v = *(const uint4*)(const void*)p;
  acc[0] += wgt * __uint_as_float(v.x << 16);
  acc[1] += wgt * __uint_as_float(v.x & 0xffff0000u);
  acc[2] += wgt * __uint_as_float(v.y << 16);
  acc[3] += wgt * __uint_as_float(v.y & 0xffff0000u);
  acc[4] += wgt * __uint_as_float(v.z << 16);
  acc[5] += wgt * __uint_as_float(v.z & 0xffff0000u);
  acc[6] += wgt * __uint_as_float(v.w << 16);
  acc[7] += wgt * __uint_as_float(v.w & 0xffff0000u);
}

__global__ __launch_bounds__(256) void rt_deform(
    const ushort16* __restrict__ value,
    const float* __restrict__ off,
    const float* __restrict__ aw,
    const float* __restrict__ ref,
    float* __restrict__ O)
{
  int gid = blockIdx.x * 256 + threadIdx.x;
  int hd0 = (gid & 3) * 8;
  int bqh = gid >> 2;
  int h   = bqh & 7;
  int bq  = bqh >> 3;
  int b   = bq / NQ_;
  const float* rp = ref + (size_t)bq * 4;
  float rx = rp[0], ry = rp[1];
  float rw = rp[2] * 0.125f, rh = rp[3] * 0.125f;
  const float* op = off + (size_t)bqh * 24;
  const float* ap = aw  + (size_t)bqh * 12;
  const ushort16* vb = value + ((size_t)b * H_ + h) * (size_t)S_ * HD_ + hd0;
  float acc[8];
#pragma unroll
  for (int i = 0; i < 8; i++) acc[i] = 0.f;
  const int starts[3] = {0, 6400, 8000};
  const int dims[3]   = {80, 40, 20};
#pragma unroll
  for (int l = 0; l < L_; l++) {
    const int Wl = dims[l];
    const ushort16* vl = vb + (size_t)starts[l] * HD_;
#pragma unroll
    for (int p = 0; p < P_; p++) {
      int ip = l * P_ + p;
      float w = ap[ip];
      float x = (rx + op[ip*2+0] * rw) * Wl - 0.5f;
      float y = (ry + op[ip*2+1] * rh) * Wl - 0.5f;
      float x0f = floorf(x), y0f = floorf(y);
      int   x0 = (int)x0f,  y0 = (int)y0f;
      float wx1 = x - x0f, wy1 = y - y0f;
      float wx0 = 1.f - wx1, wy0 = 1.f - wy1;
      bool xok0 = (x0 >= 0) & (x0 < Wl), xok1 = (x0+1 >= 0) & (x0+1 < Wl);
      bool yok0 = (y0 >= 0) & (y0 < Wl), yok1 = (y0+1 >= 0) & (y0+1 < Wl);
      const ushort16* r0p = vl + (size_t)(y0 * Wl) * HD_;
      const ushort16* r1p = r0p + (size_t)Wl * HD_;
      if (xok0 & yok0) rt_acc8(r0p + (size_t)x0 * HD_,     w * wx0 * wy0, acc);
      if (xok1 & yok0) rt_acc8(r0p + (size_t)(x0+1) * HD_, w * wx1 * wy0, acc);
      if (xok0 & yok1) rt_acc8(r1p + (size_t)x0 * HD_,     w * wx0 * wy1, acc);
      if (xok1 & yok1) rt_acc8(r1p + (size_t)(x0+1) * HD_, w * wx1 * wy1, acc);
    }
  }
  float* outp = O + (size_t)bq * D_ + h * HD_ + hd0;
  float4 a0, a1;
  a0.x = acc[0]; a0.y = acc[1]; a0.z = acc[2]; a0.w = acc[3];
  a1.x = acc[4]; a1.y = acc[5]; a1.z = acc[6]; a1.w = acc[7];
  *(float4*)outp = a0;
  *(float4*)(outp + 4) = a1;
}

// ---------- launch ----------
extern "C" void kernel_launch(void* const* d_in, const int* in_sizes, int n_in,
                              void* d_out, int out_size, void* d_ws, size_t ws_size,
                              hipStream_t stream)
{
  const float* hs   = (const float*)d_in[0];
  const float* pos  = (const float*)d_in[1];
  const float* ref  = (const float*)d_in[2];
  const float* ehs  = (const float*)d_in[3];
  const float* Wq   = (const float*)d_in[4];
  const float* Wk   = (const float*)d_in[5];
  const float* Wv   = (const float*)d_in[6];
  const float* Wo   = (const float*)d_in[7];
  const float* Woff = (const float*)d_in[8];
  const float* Waw  = (const float*)d_in[9];
  const float* Wval = (const float*)d_in[10];
  const float* Wout = (const float*)d_in[11];
  const float* W1   = (const float*)d_in[12];
  const float* W2   = (const float*)d_in[13];
  const float* bq   = (const float*)d_in[14];
  const float* bk   = (const float*)d_in[15];
  const float* bvv  = (const float*)d_in[16];
  const float* bo   = (const float*)d_in[17];
  const float* boff = (const float*)d_in[18];
  const float* baw  = (const float*)d_in[19];
  const float* bval = (const float*)d_in[20];
  const float* bout = (const float*)d_in[21];
  const float* b1   = (const float*)d_in[22];
  const float* b2   = (const float*)d_in[23];
  const float* ln1g = (const float*)d_in[24];
  const float* ln1b = (const float*)d_in[25];
  const float* ln2g = (const float*)d_in[26];
  const float* ln2b = (const float*)d_in[27];
  const float* ln3g = (const float*)d_in[28];
  const float* ln3b = (const float*)d_in[29];
  float* out = (float*)d_out;

  float* ws = (float*)d_ws;
  ushort16* value = (ushort16*)ws;
  float* hp   = ws + 34406400;
  float* t0   = ws + 36864000;
  float* t1   = ws + 39321600;
  float* hs1  = ws + 41779200;
  float* hs2  = ws + 44236800;
  float* offb = ws + 46694400;
  float* awb  = ws + 48537600;
  float* ffn1 = ws + 49459200;
  ushort16* qh = (ushort16*)(ws + 59289600);
  ushort16* kh = (ushort16*)(ws + 60600320);
  ushort16* vh = (ushort16*)(ws + 61911040);
  ushort16* vt = (ushort16*)(ws + 63221760);
  ushort16* wbase = (ushort16*)(ws + 64532480);
  ushort16* WqT   = wbase;
  ushort16* WkT   = WqT   + 65536;
  ushort16* WvT   = WkT   + 65536;
  ushort16* WoT   = WvT   + 65536;
  ushort16* WoffT = WoT   + 65536;
  ushort16* WawT  = WoffT + 65536;
  ushort16* WvalC = WawT  + 32768;   // chunk-major [k/8][col][8] bf16
  ushort16* WoutT = WvalC + 65536;
  ushort16* W1T   = WoutT + 65536;
  ushort16* W2T   = W1T   + 262144;

  const float qscale = 0.17677669529663687f;

  rt_wt<<<dim3(8, 8),  256, 0, stream>>>(Wq,   WqT,   256, 256, 256);
  rt_wt<<<dim3(8, 8),  256, 0, stream>>>(Wk,   WkT,   256, 256, 256);
  rt_wt<<<dim3(8, 8),  256, 0, stream>>>(Wv,   WvT,   256, 256, 256);
  rt_wt<<<dim3(8, 8),  256, 0, stream>>>(Wo,   WoT,   256, 256, 256);
  rt_wt<<<dim3(8, 8),  256, 0, stream>>>(Woff, WoffT, 256, 192, 256);
  rt_wt<<<dim3(4, 8),  256, 0, stream>>>(Waw,  WawT,  256,  96, 128);
  rt_wc<<<dim3(32),    256, 0, stream>>>(Wval, WvalC);
  rt_wt<<<dim3(8, 8),  256, 0, stream>>>(Wout, WoutT, 256, 256, 256);
  rt_wt<<<dim3(32, 8), 256, 0, stream>>>(W1,   W1T,   256, 1024, 1024);
  rt_wt<<<dim3(8, 32), 256, 0, stream>>>(W2,   W2T,   1024, 256, 256);

  // value projection: whole-B-in-LDS, barrier-free K-loop
  rt_vgemm<<<dim3(MV/256), 1024, 0, stream>>>(ehs, WvalC, bval, value);

  rt_add<<<dim3(M1*D_/4/256), 256, 0, stream>>>(hs, pos, hp, M1*D_/4);
  rt_mgemm<<<dim3(2, M1/GBM), 256, 0, stream>>>(hp, WqT, bq,  nullptr, qh, M1, D_, D_, qscale, 3);
  rt_mgemm<<<dim3(2, M1/GBM), 256, 0, stream>>>(hp, WkT, bk,  nullptr, kh, M1, D_, D_, 1.f, 3);
  rt_mgemm<<<dim3(2, M1/GBM), 256, 0, stream>>>(hs, WvT, bvv, nullptr, vh, M1, D_, D_, 1.f, 3);
  rt_vtr<<<dim3(B_*H_), 256, 0, stream>>>(vh, vt);
  rt_fattn<<<dim3(B_*H_*NQT/4), 256, 0, stream>>>(qh, kh, vt, t0);
  rt_mgemm<<<dim3(2, M1/GBM), 256, 0, stream>>>(t0, WoT, bo, t1, nullptr, M1, D_, D_, 1.f, 0);
  rt_ln<<<dim3(M1/4), 256, 0, stream>>>(hs, t1, ln1g, ln1b, hs1, M1);
  rt_add<<<dim3(M1*D_/4/256), 256, 0, stream>>>(hs1, pos, hp, M1*D_/4);
  rt_mgemm<<<dim3(2, M1/GBM), 256, 0, stream>>>(hp, WoffT, boff, offb, nullptr, M1, 192, D_, 1.f, 0);
  rt_mgemm<<<dim3(1, M1/GBM), 256, 0, stream>>>(hp, WawT,  baw,  awb,  nullptr, M1,  96, D_, 1.f, 0);
  rt_awsm<<<dim3(B_*NQ_*H_/256), 256, 0, stream>>>(awb, B_*NQ_*H_);
  rt_deform<<<dim3(M1*H_*4/256), 256, 0, stream>>>(value, offb, awb, ref, t0);
  rt_mgemm<<<dim3(2, M1/GBM), 256, 0, stream>>>(t0, WoutT, bout, t1, nullptr, M1, D_, D_, 1.f, 0);
  rt_ln<<<dim3(M1/4), 256, 0, stream>>>(hs1, t1, ln2g, ln2b, hs2, M1);
  rt_mgemm<<<dim3(8, M1/GBM), 256, 0, stream>>>(hs2, W1T, b1, ffn1, nullptr, M1, FFN_, D_, 1.f, 1);
  rt_mgemm<<<dim3(2, M1/GBM), 256, 0, stream>>>(ffn1, W2T, b2, t1, nullptr, M1, D_, FFN_, 1.f, 0);
  rt_ln<<<dim3(M1/4), 256, 0, stream>>>(hs2, t1, ln3g, ln3b, out, M1);
}

// Round 8
// 387.542 us; speedup vs baseline: 1.3051x; 1.2046x over previous
//
#include <hip/hip_runtime.h>
#include <hip/hip_bf16.h>

typedef unsigned int  uint32;
typedef unsigned short ushort16;
typedef __bf16 bfx8 __attribute__((ext_vector_type(8)));
typedef float  f32x4 __attribute__((ext_vector_type(4)));

typedef __attribute__((address_space(1))) const unsigned int gas_u32;
typedef __attribute__((address_space(3))) unsigned int las_u32;

#define B_   32
#define NQ_  300
#define D_   256
#define H_   8
#define HD_  32
#define L_   3
#define P_   4
#define S_   8400
#define FFN_ 1024
#define M1   (B_*NQ_)    // 9600
#define MV   (B_*S_)     // 268800
#define NQP  320
#define NQT  19

// ---------- helpers ----------
__device__ inline ushort16 f2bf(float x) {
  uint32 u = __float_as_uint(x);
  uint32 r = u + 0x7fffu + ((u >> 16) & 1u);
  return (ushort16)(r >> 16);
}
__device__ inline uint32 cvtpk(float lo, float hi) {
  uint32 r; asm("v_cvt_pk_bf16_f32 %0, %1, %2" : "=v"(r) : "v"(lo), "v"(hi)); return r;
}

// ---------- elementwise add ----------
__global__ __launch_bounds__(256) void rt_add(const float* __restrict__ a,
                                              const float* __restrict__ b,
                                              float* __restrict__ o, int n4)
{
  int i = blockIdx.x * 256 + threadIdx.x;
  if (i < n4) {
    float4 x = ((const float4*)a)[i];
    float4 y = ((const float4*)b)[i];
    float4 z; z.x = x.x + y.x; z.y = x.y + y.y; z.z = x.z + y.z; z.w = x.w + y.w;
    ((float4*)o)[i] = z;
  }
}

// ---------- fused weight prep: all transposes + Wval chunk-major + bias concats ----------
struct WPrep {
  const float* src[9];
  ushort16*    dst[9];
  int K[9], N[9], Npad[9], tileEnd[9];
  float scale[9];
  const float* wval; ushort16* wvalc;
  const float* bqs;  const float* bks;  float* bqk;
  const float* boffs; const float* baws; float* boffaw;
};

__global__ __launch_bounds__(256) void rt_wprep(WPrep a)
{
  __shared__ float t[32][33];
  int blk = blockIdx.x;
  if (blk < 904) {
    int wi = 0;
    while (blk >= a.tileEnd[wi]) wi++;
    int base = wi ? a.tileEnd[wi - 1] : 0;
    int idx = blk - base;
    int K = a.K[wi], N = a.N[wi];
    int ntx = a.Npad[wi] / 32;
    int n0 = (idx % ntx) * 32, k0 = (idx / ntx) * 32;
    float sc = a.scale[wi];
    const float* W = a.src[wi];
    ushort16* WT = a.dst[wi];
    int c = threadIdx.x & 31, r = threadIdx.x >> 5;
#pragma unroll
    for (int i = 0; i < 4; i++) {
      int nn = n0 + c;
      t[r + i * 8][c] = (nn < N) ? W[(size_t)(k0 + r + i * 8) * N + nn] : 0.f;
    }
    __syncthreads();
#pragma unroll
    for (int i = 0; i < 4; i++)
      WT[(size_t)(n0 + r + i * 8) * K + k0 + c] = f2bf(t[c][r + i * 8] * sc);
  } else if (blk < 936) {
    // Wval -> chunk-major [k/8][col][8] bf16
    int gid = (blk - 904) * 256 + threadIdx.x;
    int c = gid >> 8, n = gid & 255;
    const float* W = a.wval;
    uint4 u;
    u.x = (uint32)f2bf(W[(c*8+0)*256 + n]) | ((uint32)f2bf(W[(c*8+1)*256 + n]) << 16);
    u.y = (uint32)f2bf(W[(c*8+2)*256 + n]) | ((uint32)f2bf(W[(c*8+3)*256 + n]) << 16);
    u.z = (uint32)f2bf(W[(c*8+4)*256 + n]) | ((uint32)f2bf(W[(c*8+5)*256 + n]) << 16);
    u.w = (uint32)f2bf(W[(c*8+6)*256 + n]) | ((uint32)f2bf(W[(c*8+7)*256 + n]) << 16);
    *(uint4*)&a.wvalc[(size_t)c * 2048 + n * 8] = u;
  } else if (blk == 936) {
    a.bqk[threadIdx.x] = a.bqs[threadIdx.x] * a.scale[0];
  } else if (blk == 937) {
    a.bqk[256 + threadIdx.x] = a.bks[threadIdx.x];
  } else if (blk == 938) {
    if (threadIdx.x < 192) a.boffaw[threadIdx.x] = a.boffs[threadIdx.x];
  } else {
    if (threadIdx.x < 96) a.boffaw[192 + threadIdx.x] = a.baws[threadIdx.x];
  }
}

// ---------- persistent value GEMM: B staged once, barrier-free tile loop ----------
// grid = 256 blocks x 1024 threads; block loops over 256-row tiles.
// Swapped-operand MFMA: lane owns 1 row (l15) x 4 consecutive cols (l4*4+r) per acc quad.
__global__ __launch_bounds__(1024, 1) void rt_vgemm(
    const float* __restrict__ A, const ushort16* __restrict__ BC,
    const float* __restrict__ bias, ushort16* __restrict__ Vout)
{
  __shared__ __align__(16) char ldsB[131072];
  const int tid = threadIdx.x;
  const int lane = tid & 63, w = tid >> 6;
  const int l15 = lane & 15, l4 = lane >> 4;

  // stage all of B once (chunk-major image is LDS-linear)
#pragma unroll
  for (int i = 0; i < 8; ++i)
    __builtin_amdgcn_global_load_lds(
        (gas_u32*)(const void*)((const char*)BC + tid * 16 + i * 16384),
        (las_u32*)(void*)(&ldsB[tid * 16 + i * 16384]), 16, 0, 0);
  __syncthreads();

  const int wrow = w * 16 + l15;
  for (int t = blockIdx.x; t < MV / 256; t += 256) {
    const float* Ap = A + ((size_t)t * 256 + wrow) * 256 + l4 * 8;
    f32x4 aA = *(const f32x4*)(Ap);
    f32x4 aB = *(const f32x4*)(Ap + 4);
    f32x4 aC = *(const f32x4*)(Ap + 32);
    f32x4 aD = *(const f32x4*)(Ap + 36);
    f32x4 acc[16];
#pragma unroll
    for (int i = 0; i < 16; ++i) acc[i] = (f32x4){0.f, 0.f, 0.f, 0.f};

#pragma unroll
    for (int tt = 0; tt < 4; ++tt) {
      {
        uint4 u;
        u.x = cvtpk(aA[0], aA[1]); u.y = cvtpk(aA[2], aA[3]);
        u.z = cvtpk(aB[0], aB[1]); u.w = cvtpk(aB[2], aB[3]);
        bfx8 af = __builtin_bit_cast(bfx8, u);
        if (tt < 3) {
          aA = *(const f32x4*)(Ap + (2 * tt + 2) * 32);
          aB = *(const f32x4*)(Ap + (2 * tt + 2) * 32 + 4);
        }
        const char* bp = &ldsB[(2 * tt * 4 + l4) * 4096 + l15 * 16];
#pragma unroll
        for (int ni = 0; ni < 16; ++ni) {
          bfx8 bg = *(const bfx8*)(const void*)(bp + ni * 256);
          acc[ni] = __builtin_amdgcn_mfma_f32_16x16x32_bf16(bg, af, acc[ni], 0, 0, 0);
        }
      }
      {
        uint4 u;
        u.x = cvtpk(aC[0], aC[1]); u.y = cvtpk(aC[2], aC[3]);
        u.z = cvtpk(aD[0], aD[1]); u.w = cvtpk(aD[2], aD[3]);
        bfx8 af = __builtin_bit_cast(bfx8, u);
        if (tt < 3) {
          aC = *(const f32x4*)(Ap + (2 * tt + 3) * 32);
          aD = *(const f32x4*)(Ap + (2 * tt + 3) * 32 + 4);
        }
        const char* bp = &ldsB[((2 * tt + 1) * 4 + l4) * 4096 + l15 * 16];
#pragma unroll
        for (int ni = 0; ni < 16; ++ni) {
          bfx8 bg = *(const bfx8*)(const void*)(bp + ni * 256);
          acc[ni] = __builtin_amdgcn_mfma_f32_16x16x32_bf16(bg, af, acc[ni], 0, 0, 0);
        }
      }
    }
    // epilogue: row = t*256 + wrow; cols ni*16 + l4*4 .. +3 -> one 8B store each
    int row = t * 256 + wrow;
    int bb = row / S_, s = row - bb * S_;
    ushort16* vb = Vout + (((size_t)bb * H_) * S_ + s) * HD_;
#pragma unroll
    for (int ni = 0; ni < 16; ++ni) {
      int col = ni * 16 + l4 * 4;
      f32x4 bv = *(const f32x4*)(bias + col);
      int hh = col >> 5, hd = col & 31;
      uint2 st;
      st.x = cvtpk(acc[ni][0] + bv[0], acc[ni][1] + bv[1]);
      st.y = cvtpk(acc[ni][2] + bv[2], acc[ni][3] + bv[3]);
      *(uint2*)(vb + (size_t)hh * S_ * HD_ + hd) = st;
    }
  }
}

// ---------- MFMA bf16 GEMM (generic) ----------
// mode 0: f32 C. mode 1: f32 C + relu. mode 3: bf16 scatter [b][h][NQP][hd].
// mode 4: dual scatter (cols 0..255 -> Sc=qh, 256..511 -> Sc2=kh).
#define GBM 128
#define GBN 128
#define GBK 32
#define LDP 40

__global__ __launch_bounds__(256) void rt_mgemm(
    const float* __restrict__ A, const ushort16* __restrict__ BT,
    const float* __restrict__ bias, float* __restrict__ C,
    ushort16* __restrict__ Sc, ushort16* __restrict__ Sc2,
    int M, int N, int K, float scale, int mode)
{
  __shared__ __align__(16) ushort16 As[GBM][LDP];
  __shared__ __align__(16) ushort16 Bs[GBN][LDP];
  const int tid  = threadIdx.x;
  const int lane = tid & 63;
  const int w    = tid >> 6;
  const int wr   = (w >> 1) * 64;
  const int wc   = (w & 1) * 64;
  const int bm   = blockIdx.y * GBM;
  const int bn   = blockIdx.x * GBN;
  const int l15  = lane & 15;
  const int l4   = lane >> 4;

  f32x4 acc[4][4];
#pragma unroll
  for (int i = 0; i < 4; i++)
#pragma unroll
    for (int j = 0; j < 4; j++)
      acc[i][j] = (f32x4){0.f, 0.f, 0.f, 0.f};

  const int arow = tid >> 3, akc = tid & 7;
  const int brow = tid >> 2, bkc = tid & 3;

  for (int k0 = 0; k0 < K; k0 += GBK) {
#pragma unroll
    for (int i = 0; i < 4; i++) {
      int row = arow + i * 32;
      f32x4 v = *(const f32x4*)(A + (size_t)(bm + row) * K + k0 + akc * 4);
      uint2 u;
      u.x = cvtpk(v.x, v.y);
      u.y = cvtpk(v.z, v.w);
      *(uint2*)(&As[row][akc * 4]) = u;
    }
#pragma unroll
    for (int i = 0; i < 2; i++) {
      int row = brow + i * 64;
      uint4 v = *(const uint4*)(BT + (size_t)(bn + row) * K + k0 + bkc * 8);
      *(uint4*)(&Bs[row][bkc * 8]) = v;
    }
    __syncthreads();

    bfx8 af[4], bg[4];
#pragma unroll
    for (int mi = 0; mi < 4; mi++)
      af[mi] = *(const bfx8*)(&As[wr + mi * 16 + l15][l4 * 8]);
#pragma unroll
    for (int ni = 0; ni < 4; ni++)
      bg[ni] = *(const bfx8*)(&Bs[wc + ni * 16 + l15][l4 * 8]);
#pragma unroll
    for (int mi = 0; mi < 4; mi++)
#pragma unroll
      for (int ni = 0; ni < 4; ni++)
        acc[mi][ni] = __builtin_amdgcn_mfma_f32_16x16x32_bf16(af[mi], bg[ni], acc[mi][ni], 0, 0, 0);
    __syncthreads();
  }

#pragma unroll
  for (int mi = 0; mi < 4; mi++) {
#pragma unroll
    for (int ni = 0; ni < 4; ni++) {
      int col = bn + wc + ni * 16 + l15;
      if (col >= N) continue;
      float bv = bias[col];
#pragma unroll
      for (int r = 0; r < 4; r++) {
        int row = bm + wr + mi * 16 + l4 * 4 + r;
        float vv = (acc[mi][ni][r] + bv) * scale;
        if (mode == 1) vv = fmaxf(vv, 0.f);
        if (mode == 3) {
          int bb = row / NQ_, q = row - bb * NQ_;
          int hh = col >> 5, hd = col & 31;
          Sc[(((size_t)bb * H_ + hh) * NQP + q) * HD_ + hd] = f2bf(vv);
        } else if (mode == 4) {
          int bb = row / NQ_, q = row - bb * NQ_;
          int hh = col >> 5, hd = col & 31;
          ushort16* d = (hh < 8) ? Sc : Sc2;
          d[(((size_t)bb * H_ + (hh & 7)) * NQP + q) * HD_ + hd] = f2bf(vv);
        } else {
          C[(size_t)row * N + col] = vv;
        }
      }
    }
  }
}

// ---------- V transpose per (b,h) ----------
__global__ __launch_bounds__(256) void rt_vtr(const ushort16* __restrict__ vh,
                                              ushort16* __restrict__ vt)
{
  __shared__ ushort16 t[64][33];
  int bh = blockIdx.x;
  const ushort16* src = vh + (size_t)bh * NQP * HD_;
  ushort16* dst = vt + (size_t)bh * HD_ * NQP;
  int tid = threadIdx.x;
  int lrow = tid >> 2, lc8 = (tid & 3) * 8;
  int ohd = tid >> 3, oq8 = (tid & 7) * 8;
  for (int r0 = 0; r0 < NQP; r0 += 64) {
    uint4 v = *(const uint4*)(src + (size_t)(r0 + lrow) * HD_ + lc8);
    ushort16* tp = &t[lrow][lc8];
    tp[0] = (ushort16)(v.x & 0xffff); tp[1] = (ushort16)(v.x >> 16);
    tp[2] = (ushort16)(v.y & 0xffff); tp[3] = (ushort16)(v.y >> 16);
    tp[4] = (ushort16)(v.z & 0xffff); tp[5] = (ushort16)(v.z >> 16);
    tp[6] = (ushort16)(v.w & 0xffff); tp[7] = (ushort16)(v.w >> 16);
    __syncthreads();
    uint4 o;
    o.x = (uint32)t[oq8 + 0][ohd] | ((uint32)t[oq8 + 1][ohd] << 16);
    o.y = (uint32)t[oq8 + 2][ohd] | ((uint32)t[oq8 + 3][ohd] << 16);
    o.z = (uint32)t[oq8 + 4][ohd] | ((uint32)t[oq8 + 5][ohd] << 16);
    o.w = (uint32)t[oq8 + 6][ohd] | ((uint32)t[oq8 + 7][ohd] << 16);
    *(uint4*)(dst + (size_t)ohd * NQP + r0 + oq8) = o;
    __syncthreads();
  }
}

// ---------- MFMA flash self-attention ----------
__global__ __launch_bounds__(256) void rt_fattn(
    const ushort16* __restrict__ qh, const ushort16* __restrict__ kh,
    const ushort16* __restrict__ vt, float* __restrict__ O)
{
  int gw  = blockIdx.x * 4 + (threadIdx.x >> 6);
  int bh  = gw / NQT, qt = gw - bh * NQT;
  int b   = bh >> 3, h = bh & 7;
  int lane = threadIdx.x & 63;
  int l15 = lane & 15, l4 = lane >> 4;
  int kb4 = l4 * 4;
  const ushort16* Qb = qh + (size_t)bh * NQP * HD_;
  const ushort16* Kb = kh + (size_t)bh * NQP * HD_;
  const ushort16* Vb = vt + (size_t)bh * HD_ * NQP;
  int q = qt * 16 + l15;

  bfx8 bgQ = *(const bfx8*)(const void*)(Qb + (size_t)q * HD_ + l4 * 8);
  f32x4 o0 = {0.f,0.f,0.f,0.f}, o1 = {0.f,0.f,0.f,0.f};
  float m = -1e30f, ssum = 0.f;

  for (int k0 = 0; k0 < NQP; k0 += 32) {
    bfx8 afk0 = *(const bfx8*)(const void*)(Kb + (size_t)(k0 + l15) * HD_ + l4 * 8);
    bfx8 afk1 = *(const bfx8*)(const void*)(Kb + (size_t)(k0 + 16 + l15) * HD_ + l4 * 8);
    f32x4 z = {0.f,0.f,0.f,0.f};
    f32x4 s0 = __builtin_amdgcn_mfma_f32_16x16x32_bf16(afk0, bgQ, z, 0, 0, 0);
    f32x4 s1 = __builtin_amdgcn_mfma_f32_16x16x32_bf16(afk1, bgQ, z, 0, 0, 0);
    int ka = k0 + kb4, kbb = k0 + 16 + kb4;
#pragma unroll
    for (int r = 0; r < 4; r++) {
      if (ka  + r >= NQ_) s0[r] = -1e30f;
      if (kbb + r >= NQ_) s1[r] = -1e30f;
    }
    float cm = fmaxf(fmaxf(fmaxf(s0[0], s0[1]), fmaxf(s0[2], s0[3])),
                     fmaxf(fmaxf(s1[0], s1[1]), fmaxf(s1[2], s1[3])));
    cm = fmaxf(cm, __shfl_xor(cm, 16));
    cm = fmaxf(cm, __shfl_xor(cm, 32));
    float nm = fmaxf(m, cm);
    float sc = __expf(m - nm);
    m = nm;
    f32x4 p0, p1;
#pragma unroll
    for (int r = 0; r < 4; r++) { p0[r] = __expf(s0[r] - m); p1[r] = __expf(s1[r] - m); }
    float ls = (p0[0]+p0[1]+p0[2]+p0[3]) + (p1[0]+p1[1]+p1[2]+p1[3]);
    ls += __shfl_xor(ls, 16);
    ls += __shfl_xor(ls, 32);
    ssum = ssum * sc + ls;

    uint32 t0w0 = cvtpk(p0[0], p0[1]);
    uint32 t0w1 = cvtpk(p0[2], p0[3]);
    uint32 t1w0 = cvtpk(p1[0], p1[1]);
    uint32 t1w1 = cvtpk(p1[2], p1[3]);
    int srcA = l15 + 32 * (l4 & 1);
    int srcB = srcA + 16;
    uint32 a00 = __shfl((int)t0w0, srcA), a01 = __shfl((int)t0w1, srcA);
    uint32 b00 = __shfl((int)t0w0, srcB), b01 = __shfl((int)t0w1, srcB);
    uint32 a10 = __shfl((int)t1w0, srcA), a11 = __shfl((int)t1w1, srcA);
    uint32 b10 = __shfl((int)t1w0, srcB), b11 = __shfl((int)t1w1, srcB);
    bool hi = (l4 >= 2);
    uint4 pw;
    pw.x = hi ? a10 : a00;
    pw.y = hi ? a11 : a01;
    pw.z = hi ? b10 : b00;
    pw.w = hi ? b11 : b01;
    bfx8 bgP = __builtin_bit_cast(bfx8, pw);

    bfx8 afv0 = *(const bfx8*)(const void*)(Vb + (size_t)l15 * NQP + k0 + l4 * 8);
    bfx8 afv1 = *(const bfx8*)(const void*)(Vb + (size_t)(16 + l15) * NQP + k0 + l4 * 8);
#pragma unroll
    for (int r = 0; r < 4; r++) { o0[r] *= sc; o1[r] *= sc; }
    o0 = __builtin_amdgcn_mfma_f32_16x16x32_bf16(afv0, bgP, o0, 0, 0, 0);
    o1 = __builtin_amdgcn_mfma_f32_16x16x32_bf16(afv1, bgP, o1, 0, 0, 0);
  }

  if (q < NQ_) {
    float inv = 1.f / ssum;
    float* op = O + ((size_t)(b * NQ_ + q)) * D_ + h * HD_ + kb4;
    f32x4 r0, r1;
#pragma unroll
    for (int r = 0; r < 4; r++) { r0[r] = o0[r] * inv; r1[r] = o1[r] * inv; }
    *(f32x4*)op = r0;
    *(f32x4*)(op + 16) = r1;
  }
}

// ---------- LayerNorm ----------
__global__ __launch_bounds__(256) void rt_ln(
    const float* __restrict__ X, const float* __restrict__ R,
    const float* __restrict__ g, const float* __restrict__ be,
    float* __restrict__ O, int rows)
{
  int row = blockIdx.x * 4 + (threadIdx.x >> 6);
  int lane = threadIdx.x & 63;
  if (row >= rows) return;
  size_t base = (size_t)row * D_ + lane * 4;
  float4 x = *(const float4*)(X + base);
  float4 r = *(const float4*)(R + base);
  float v0 = x.x + r.x, v1 = x.y + r.y, v2 = x.z + r.z, v3 = x.w + r.w;
  float s = v0 + v1 + v2 + v3;
  float sq = v0*v0 + v1*v1 + v2*v2 + v3*v3;
#pragma unroll
  for (int o = 32; o >= 1; o >>= 1) { s += __shfl_xor(s, o); sq += __shfl_xor(sq, o); }
  float mean = s * (1.f / D_);
  float var  = sq * (1.f / D_) - mean * mean;
  float inv  = 1.f / sqrtf(var + 1e-5f);
  int c = lane * 4;
  float4 gv = *(const float4*)(g + c);
  float4 bv = *(const float4*)(be + c);
  float4 o4;
  o4.x = (v0 - mean) * inv * gv.x + bv.x;
  o4.y = (v1 - mean) * inv * gv.y + bv.y;
  o4.z = (v2 - mean) * inv * gv.z + bv.z;
  o4.w = (v3 - mean) * inv * gv.w + bv.w;
  *(float4*)(O + base) = o4;
}

// ---------- deformable sampling (aw softmax folded in) ----------
__device__ inline void rt_acc8(const ushort16* p, float wgt, float* acc) {
  uint4 v = *(const uint4*)(const void*)p;
  acc[0] += wgt * __uint_as_float(v.x << 16);
  acc[1] += wgt * __uint_as_float(v.x & 0xffff0000u);
  acc[2] += wgt * __uint_as_float(v.y << 16);
  acc[3] += wgt * __uint_as_float(v.y & 0xffff0000u);
  acc[4] += wgt * __uint_as_float(v.z << 16);
  acc[5] += wgt * __uint_as_float(v.z & 0xffff0000u);
  acc[6] += wgt * __uint_as_float(v.w << 16);
  acc[7] += wgt * __uint_as_float(v.w & 0xffff0000u);
}

__global__ __launch_bounds__(256) void rt_deform(
    const ushort16* __restrict__ value,   // [B][H][S][HD] bf16
    const float* __restrict__ offaw,      // [B*NQ][288]: 192 off + 96 aw logits
    const float* __restrict__ ref,        // [B][NQ][1][4]
    float* __restrict__ O)                // [B][NQ][D]
{
  int gid = blockIdx.x * 256 + threadIdx.x;   // M1*H*4 threads
  int hd0 = (gid & 3) * 8;
  int bqh = gid >> 2;
  int h   = bqh & 7;
  int bq  = bqh >> 3;
  int b   = bq / NQ_;
  const float* rp = ref + (size_t)bq * 4;
  float rx = rp[0], ry = rp[1];
  float rw = rp[2] * 0.125f, rh = rp[3] * 0.125f;
  const float* op = offaw + (size_t)bq * 288 + h * 24;
  const float* ap = offaw + (size_t)bq * 288 + 192 + h * 12;
  // inline softmax over the 12 logits
  float e[12]; float mx = -1e30f;
#pragma unroll
  for (int i = 0; i < 12; i++) { e[i] = ap[i]; mx = fmaxf(mx, e[i]); }
  float ssum = 0.f;
#pragma unroll
  for (int i = 0; i < 12; i++) { e[i] = __expf(e[i] - mx); ssum += e[i]; }
  float sinv = 1.f / ssum;

  const ushort16* vb = value + ((size_t)b * H_ + h) * (size_t)S_ * HD_ + hd0;
  float acc[8];
#pragma unroll
  for (int i = 0; i < 8; i++) acc[i] = 0.f;
  const int starts[3] = {0, 6400, 8000};
  const int dims[3]   = {80, 40, 20};
#pragma unroll
  for (int l = 0; l < L_; l++) {
    const int Wl = dims[l];
    const ushort16* vl = vb + (size_t)starts[l] * HD_;
#pragma unroll
    for (int p = 0; p < P_; p++) {
      int ip = l * P_ + p;
      float wgt = e[ip] * sinv;
      float x = (rx + op[ip*2+0] * rw) * Wl - 0.5f;
      float y = (ry + op[ip*2+1] * rh) * Wl - 0.5f;
      float x0f = floorf(x), y0f = floorf(y);
      int   x0 = (int)x0f,  y0 = (int)y0f;
      float wx1 = x - x0f, wy1 = y - y0f;
      float wx0 = 1.f - wx1, wy0 = 1.f - wy1;
      bool xok0 = (x0 >= 0) & (x0 < Wl), xok1 = (x0+1 >= 0) & (x0+1 < Wl);
      bool yok0 = (y0 >= 0) & (y0 < Wl), yok1 = (y0+1 >= 0) & (y0+1 < Wl);
      const ushort16* r0p = vl + (size_t)(y0 * Wl) * HD_;
      const ushort16* r1p = r0p + (size_t)Wl * HD_;
      if (xok0 & yok0) rt_acc8(r0p + (size_t)x0 * HD_,     wgt * wx0 * wy0, acc);
      if (xok1 & yok0) rt_acc8(r0p + (size_t)(x0+1) * HD_, wgt * wx1 * wy0, acc);
      if (xok0 & yok1) rt_acc8(r1p + (size_t)x0 * HD_,     wgt * wx0 * wy1, acc);
      if (xok1 & yok1) rt_acc8(r1p + (size_t)(x0+1) * HD_, wgt * wx1 * wy1, acc);
    }
  }
  float* outp = O + (size_t)bq * D_ + h * HD_ + hd0;
  float4 a0, a1;
  a0.x = acc[0]; a0.y = acc[1]; a0.z = acc[2]; a0.w = acc[3];
  a1.x = acc[4]; a1.y = acc[5]; a1.z = acc[6]; a1.w = acc[7];
  *(float4*)outp = a0;
  *(float4*)(outp + 4) = a1;
}

// ---------- launch ----------
extern "C" void kernel_launch(void* const* d_in, const int* in_sizes, int n_in,
                              void* d_out, int out_size, void* d_ws, size_t ws_size,
                              hipStream_t stream)
{
  const float* hs   = (const float*)d_in[0];
  const float* pos  = (const float*)d_in[1];
  const float* ref  = (const float*)d_in[2];
  const float* ehs  = (const float*)d_in[3];
  const float* Wq   = (const float*)d_in[4];
  const float* Wk   = (const float*)d_in[5];
  const float* Wv   = (const float*)d_in[6];
  const float* Wo   = (const float*)d_in[7];
  const float* Woff = (const float*)d_in[8];
  const float* Waw  = (const float*)d_in[9];
  const float* Wval = (const float*)d_in[10];
  const float* Wout = (const float*)d_in[11];
  const float* W1   = (const float*)d_in[12];
  const float* W2   = (const float*)d_in[13];
  const float* bq   = (const float*)d_in[14];
  const float* bk   = (const float*)d_in[15];
  const float* bvv  = (const float*)d_in[16];
  const float* bo   = (const float*)d_in[17];
  const float* boff = (const float*)d_in[18];
  const float* baw  = (const float*)d_in[19];
  const float* bval = (const float*)d_in[20];
  const float* bout = (const float*)d_in[21];
  const float* b1   = (const float*)d_in[22];
  const float* b2   = (const float*)d_in[23];
  const float* ln1g = (const float*)d_in[24];
  const float* ln1b = (const float*)d_in[25];
  const float* ln2g = (const float*)d_in[26];
  const float* ln2b = (const float*)d_in[27];
  const float* ln3g = (const float*)d_in[28];
  const float* ln3b = (const float*)d_in[29];
  float* out = (float*)d_out;

  float* ws = (float*)d_ws;
  ushort16* value = (ushort16*)ws;                 // [B][H][S][HD] bf16
  float* hp     = ws + 34406400;
  float* t0     = ws + 36864000;
  float* t1     = ws + 39321600;
  float* hs1    = ws + 41779200;
  float* hs2    = ws + 44236800;
  float* offawb = ws + 46694400;                   // [M1][288]
  float* ffn1   = ws + 49459200;                   // [M1][1024] -> ends 59289600
  ushort16* qh = (ushort16*)(ws + 59289600);
  ushort16* kh = (ushort16*)(ws + 60600320);
  ushort16* vh = (ushort16*)(ws + 61911040);
  ushort16* vt = (ushort16*)(ws + 63221760);
  ushort16* wbase  = (ushort16*)(ws + 64532480);
  ushort16* WqkT   = wbase;                        // [512][256]
  ushort16* WvT    = WqkT   + 131072;
  ushort16* WoT    = WvT    + 65536;
  ushort16* WoffawT= WoT    + 65536;               // [384][256] (rows 288+ unused)
  ushort16* WoutT  = WoffawT+ 98304;
  ushort16* W1T    = WoutT  + 65536;               // [1024][256]
  ushort16* W2T    = W1T    + 262144;              // [256][1024]
  ushort16* WvalC  = W2T    + 262144;              // chunk-major
  float* bqk    = (float*)(WvalC + 65536);         // [512]
  float* boffaw = bqk + 512;                       // [288]

  const float qscale = 0.17677669529663687f;

  // fused weight prep (1 launch)
  WPrep a;
  a.src[0]=Wq;   a.dst[0]=WqkT;            a.K[0]=256;  a.N[0]=256;  a.Npad[0]=256; a.scale[0]=qscale;
  a.src[1]=Wk;   a.dst[1]=WqkT+65536;      a.K[1]=256;  a.N[1]=256;  a.Npad[1]=256; a.scale[1]=1.f;
  a.src[2]=Wv;   a.dst[2]=WvT;             a.K[2]=256;  a.N[2]=256;  a.Npad[2]=256; a.scale[2]=1.f;
  a.src[3]=Wo;   a.dst[3]=WoT;             a.K[3]=256;  a.N[3]=256;  a.Npad[3]=256; a.scale[3]=1.f;
  a.src[4]=Woff; a.dst[4]=WoffawT;         a.K[4]=256;  a.N[4]=192;  a.Npad[4]=192; a.scale[4]=1.f;
  a.src[5]=Waw;  a.dst[5]=WoffawT+49152;   a.K[5]=256;  a.N[5]=96;   a.Npad[5]=96;  a.scale[5]=1.f;
  a.src[6]=Wout; a.dst[6]=WoutT;           a.K[6]=256;  a.N[6]=256;  a.Npad[6]=256; a.scale[6]=1.f;
  a.src[7]=W1;   a.dst[7]=W1T;             a.K[7]=256;  a.N[7]=1024; a.Npad[7]=1024;a.scale[7]=1.f;
  a.src[8]=W2;   a.dst[8]=W2T;             a.K[8]=1024; a.N[8]=256;  a.Npad[8]=256; a.scale[8]=1.f;
  int cum = 0;
  int tiles[9] = {64, 64, 64, 64, 48, 24, 64, 256, 256};
  for (int i = 0; i < 9; i++) { cum += tiles[i]; a.tileEnd[i] = cum; }   // 904
  a.wval = Wval; a.wvalc = WvalC;
  a.bqs = bq; a.bks = bk; a.bqk = bqk;
  a.boffs = boff; a.baws = baw; a.boffaw = boffaw;
  rt_wprep<<<dim3(940), 256, 0, stream>>>(a);

  // value projection: persistent, B-in-LDS once
  rt_vgemm<<<dim3(256), 1024, 0, stream>>>(ehs, WvalC, bval, value);

  rt_add<<<dim3(M1*D_/4/256), 256, 0, stream>>>(hs, pos, hp, M1*D_/4);
  // fused q+k projection (512 cols), v projection
  rt_mgemm<<<dim3(4, M1/GBM), 256, 0, stream>>>(hp, WqkT, bqk, nullptr, qh, kh, M1, 512, D_, 1.f, 4);
  rt_mgemm<<<dim3(2, M1/GBM), 256, 0, stream>>>(hs, WvT, bvv, nullptr, vh, vh, M1, D_, D_, 1.f, 3);
  rt_vtr<<<dim3(B_*H_), 256, 0, stream>>>(vh, vt);
  rt_fattn<<<dim3(B_*H_*NQT/4), 256, 0, stream>>>(qh, kh, vt, t0);
  rt_mgemm<<<dim3(2, M1/GBM), 256, 0, stream>>>(t0, WoT, bo, t1, nullptr, nullptr, M1, D_, D_, 1.f, 0);
  rt_ln<<<dim3(M1/4), 256, 0, stream>>>(hs, t1, ln1g, ln1b, hs1, M1);
  rt_add<<<dim3(M1*D_/4/256), 256, 0, stream>>>(hs1, pos, hp, M1*D_/4);
  // fused off+aw projection (288 cols)
  rt_mgemm<<<dim3(3, M1/GBM), 256, 0, stream>>>(hp, WoffawT, boffaw, offawb, nullptr, nullptr, M1, 288, D_, 1.f, 0);
  rt_deform<<<dim3(M1*H_*4/256), 256, 0, stream>>>(value, offawb, ref, t0);
  rt_mgemm<<<dim3(2, M1/GBM), 256, 0, stream>>>(t0, WoutT, bout, t1, nullptr, nullptr, M1, D_, D_, 1.f, 0);
  rt_ln<<<dim3(M1/4), 256, 0, stream>>>(hs1, t1, ln2g, ln2b, hs2, M1);
  rt_mgemm<<<dim3(8, M1/GBM), 256, 0, stream>>>(hs2, W1T, b1, ffn1, nullptr, nullptr, M1, FFN_, D_, 1.f, 1);
  rt_mgemm<<<dim3(2, M1/GBM), 256, 0, stream>>>(ffn1, W2T, b2, t1, nullptr, nullptr, M1, D_, FFN_, 1.f, 0);
  rt_ln<<<dim3(M1/4), 256, 0, stream>>>(hs2, t1, ln3g, ln3b, out, M1);
}